// Round 1
// baseline (1522.493 us; speedup 1.0000x reference)
//
#include <hip/hip_runtime.h>
#include <cstddef>

#define TPB 256

// ---------------- K0: merge conv weights ----------------
__global__ __launch_bounds__(TPB) void prep_weights(
    const float* __restrict__ w1, const float* __restrict__ b1,
    const float* __restrict__ w3, const float* __restrict__ b3,
    const float* __restrict__ w5, const float* __restrict__ b5,
    float* __restrict__ w_eff, float* __restrict__ b_eff) {
  int idx = blockIdx.x * TPB + threadIdx.x;
  if (idx < 256 * 256 * 25) {
    int kk = idx % 25;
    int oc = idx / 25;
    int kh = kk / 5, kw = kk % 5;
    float v = w5[idx];
    if (kh >= 1 && kh <= 3 && kw >= 1 && kw <= 3)
      v += w3[oc * 9 + (kh - 1) * 3 + (kw - 1)];
    if (kh == 2 && kw == 2) v += w1[oc];
    w_eff[idx] = v;
  }
  if (idx < 256) b_eff[idx] = b1[idx] + b3[idx] + b5[idx];
}

// ---------------- K1: fused 5x5 conv (pad 2) ----------------
// grid (16 o-tiles, 2 h-halves, 16 b), block 256.
// Each block: 16 out-channels x 16 rows x 32 cols. LDS: 8 in-ch x 20x36 halo tile.
__global__ __launch_bounds__(TPB) void conv5(
    const float* __restrict__ x, const float* __restrict__ w_eff,
    const float* __restrict__ b_eff, float* __restrict__ out) {
  const int o0 = blockIdx.x * 16;
  const int h0 = blockIdx.y * 16;
  const int b = blockIdx.z;
  const int tid = threadIdx.x;
  __shared__ float xs[8 * 720];  // 8 ch * 20 rows * 36 cols
  float acc[16][2];
#pragma unroll
  for (int o = 0; o < 16; ++o) { acc[o][0] = 0.f; acc[o][1] = 0.f; }
  const int lh0 = tid >> 5, lw = tid & 31;
  const int base0 = lh0 * 36 + lw;
  const int base1 = (lh0 + 8) * 36 + lw;
  for (int c0 = 0; c0 < 256; c0 += 8) {
    __syncthreads();
    for (int e = tid; e < 8 * 720; e += TPB) {
      int c = e / 720, s = e - c * 720;
      int ih = h0 + s / 36 - 2;
      int iw = (s % 36) - 2;
      float v = 0.f;
      if ((unsigned)ih < 32u && (unsigned)iw < 32u)
        v = x[(((size_t)b * 256 + c0 + c) * 32 + ih) * 32 + iw];
      xs[e] = v;
    }
    __syncthreads();
    for (int c = 0; c < 8; ++c) {
      const float* xc = &xs[c * 720];
      const float* wp = w_eff + ((size_t)o0 * 256 + (c0 + c)) * 25;
      for (int kh = 0; kh < 5; ++kh) {
#pragma unroll
        for (int kw = 0; kw < 5; ++kw) {
          float x0 = xc[base0 + kh * 36 + kw];
          float x1 = xc[base1 + kh * 36 + kw];
#pragma unroll
          for (int o = 0; o < 16; ++o) {
            float wv = wp[(size_t)o * 6400 + kh * 5 + kw];
            acc[o][0] = fmaf(x0, wv, acc[o][0]);
            acc[o][1] = fmaf(x1, wv, acc[o][1]);
          }
        }
      }
    }
  }
#pragma unroll
  for (int o = 0; o < 16; ++o) {
    float bv = b_eff[o0 + o];
    size_t rowbase = ((size_t)b * 256 + o0 + o) * 1024 + (size_t)h0 * 32;
    out[rowbase + tid] = acc[o][0] + bv;
    out[rowbase + 256 + tid] = acc[o][1] + bv;
  }
}

// ---------------- K2: per-(b,c) avg+max pool ----------------
__global__ __launch_bounds__(TPB) void pool_avgmax(
    const float* __restrict__ out, float* __restrict__ avg, float* __restrict__ mx) {
  int bc = blockIdx.x;
  int tid = threadIdx.x;
  const float4 v = ((const float4*)(out + (size_t)bc * 1024))[tid];
  float s = v.x + v.y + v.z + v.w;
  float m = fmaxf(fmaxf(v.x, v.y), fmaxf(v.z, v.w));
#pragma unroll
  for (int off = 1; off < 64; off <<= 1) {
    s += __shfl_xor(s, off);
    m = fmaxf(m, __shfl_xor(m, off));
  }
  __shared__ float ss[4], ms[4];
  if ((tid & 63) == 0) { ss[tid >> 6] = s; ms[tid >> 6] = m; }
  __syncthreads();
  if (tid == 0) {
    s = ss[0] + ss[1] + ss[2] + ss[3];
    m = fmaxf(fmaxf(ms[0], ms[1]), fmaxf(ms[2], ms[3]));
    avg[bc] = s * (1.f / 1024.f);
    mx[bc] = m;
  }
}

// ---------------- K3: channel-attention MLP ----------------
__global__ __launch_bounds__(TPB) void ca_mlp(
    const float* __restrict__ avg, const float* __restrict__ mx,
    const float* __restrict__ w1, const float* __restrict__ w2,
    float* __restrict__ ca) {
  int b = blockIdx.x;
  int t = threadIdx.x;
  __shared__ float av[256], mv[256], h[16];
  av[t] = avg[b * 256 + t];
  mv[t] = mx[b * 256 + t];
  __syncthreads();
  if (t < 16) {
    float ha = 0.f, hm = 0.f;
    for (int c = 0; c < 256; ++c) {
      float wv = w1[t * 256 + c];
      ha += wv * av[c];
      hm += wv * mv[c];
    }
    h[t] = fmaxf(ha, 0.f) + fmaxf(hm, 0.f);  // w2 linear: sum of relus
  }
  __syncthreads();
  float s = 0.f;
#pragma unroll
  for (int j = 0; j < 16; ++j) s += w2[t * 16 + j] * h[j];
  ca[b * 256 + t] = 1.f / (1.f + __expf(-s));
}

// ---------------- K4: c = out * ca ----------------
__global__ __launch_bounds__(TPB) void mul_ca(
    const float* __restrict__ out, const float* __restrict__ ca,
    float* __restrict__ cbuf) {
  int i = blockIdx.x * TPB + threadIdx.x;  // float4 index over 1048576
  float4 v = ((const float4*)out)[i];
  float g = ca[i >> 8];
  v.x *= g; v.y *= g; v.z *= g; v.w *= g;
  ((float4*)cbuf)[i] = v;
}

// ---------------- K5: spatial mean/max over channels ----------------
__global__ __launch_bounds__(TPB) void spatial_pool(
    const float* __restrict__ cbuf, float* __restrict__ sa_in) {
  int i = blockIdx.x * TPB + threadIdx.x;  // B*N
  int b = i >> 10, pix = i & 1023;
  const float* p = cbuf + (size_t)b * 262144 + pix;
  float s = 0.f, m = -3.4e38f;
  for (int ch = 0; ch < 256; ++ch) {
    float v = p[(size_t)ch * 1024];
    s += v;
    m = fmaxf(m, v);
  }
  sa_in[b * 2048 + pix] = s * (1.f / 256.f);
  sa_in[b * 2048 + 1024 + pix] = m;
}

// ---------------- K6: 7x7 spatial-attn conv + sigmoid ----------------
__global__ __launch_bounds__(TPB) void sa_conv(
    const float* __restrict__ sa_in, const float* __restrict__ sw,
    float* __restrict__ sa) {
  int i = blockIdx.x * TPB + threadIdx.x;  // B*N
  int b = i >> 10, pix = i & 1023;
  int h = pix >> 5, w = pix & 31;
  float s = 0.f;
#pragma unroll
  for (int ci = 0; ci < 2; ++ci)
    for (int kh = 0; kh < 7; ++kh) {
      int ih = h + kh - 3;
      if ((unsigned)ih >= 32u) continue;
#pragma unroll
      for (int kw = 0; kw < 7; ++kw) {
        int iw = w + kw - 3;
        if ((unsigned)iw >= 32u) continue;
        s += sa_in[b * 2048 + ci * 1024 + ih * 32 + iw] * sw[ci * 49 + kh * 7 + kw];
      }
    }
  sa[i] = 1.f / (1.f + __expf(-s));
}

// ---------------- K7: cbam = c * sa ----------------
__global__ __launch_bounds__(TPB) void mul_sa(
    float* __restrict__ cbuf, const float* __restrict__ sa) {
  int i = blockIdx.x * TPB + threadIdx.x;  // float4 index over 1048576
  int b = i >> 16;
  float4 g = ((const float4*)(sa + (size_t)b * 1024))[i & 255];
  float4 v = ((float4*)cbuf)[i];
  v.x *= g.x; v.y *= g.y; v.z *= g.z; v.w *= g.w;
  ((float4*)cbuf)[i] = v;
}

// ---------------- GEMM: Y[b][o][n] = bias[o] + sum_k W[o,k] * X[b,k,n] ----------------
// X source: k<256 -> Xa, else Xb (each [B,256,1024]). grid (N/64, O/64, B).
__global__ __launch_bounds__(TPB) void gemm1x1(
    const float* __restrict__ Wm, const float* __restrict__ bias,
    const float* __restrict__ Xa, const float* __restrict__ Xb,
    float* __restrict__ Y, int O, int K) {
  int tid = threadIdx.x;
  int n0 = blockIdx.x * 64, o0 = blockIdx.y * 64, b = blockIdx.z;
  __shared__ float Ws[16][68];
  __shared__ float Xs[16][64];
  float acc[4][4] = {};
  int to = tid & 15, tn = tid >> 4;
  for (int k0 = 0; k0 < K; k0 += 16) {
    const float* Xp = Xa;
    int kof = k0;
    if (k0 >= 256) { Xp = Xb; kof = k0 - 256; }
    __syncthreads();
    {
      int e = tid;
#pragma unroll
      for (int r = 0; r < 4; ++r, e += TPB) {
        int kk = e & 15, o = e >> 4;
        Ws[kk][o] = Wm[(size_t)(o0 + o) * K + k0 + kk];
      }
      e = tid;
#pragma unroll
      for (int r = 0; r < 4; ++r, e += TPB) {
        int nn = e & 63, kk = e >> 6;
        Xs[kk][nn] = Xp[((size_t)b * 256 + kof + kk) * 1024 + n0 + nn];
      }
    }
    __syncthreads();
#pragma unroll
    for (int kk = 0; kk < 16; ++kk) {
      float4 wv = *(const float4*)&Ws[kk][to * 4];
      float4 xv = *(const float4*)&Xs[kk][tn * 4];
      acc[0][0] = fmaf(wv.x, xv.x, acc[0][0]); acc[0][1] = fmaf(wv.x, xv.y, acc[0][1]);
      acc[0][2] = fmaf(wv.x, xv.z, acc[0][2]); acc[0][3] = fmaf(wv.x, xv.w, acc[0][3]);
      acc[1][0] = fmaf(wv.y, xv.x, acc[1][0]); acc[1][1] = fmaf(wv.y, xv.y, acc[1][1]);
      acc[1][2] = fmaf(wv.y, xv.z, acc[1][2]); acc[1][3] = fmaf(wv.y, xv.w, acc[1][3]);
      acc[2][0] = fmaf(wv.z, xv.x, acc[2][0]); acc[2][1] = fmaf(wv.z, xv.y, acc[2][1]);
      acc[2][2] = fmaf(wv.z, xv.z, acc[2][2]); acc[2][3] = fmaf(wv.z, xv.w, acc[2][3]);
      acc[3][0] = fmaf(wv.w, xv.x, acc[3][0]); acc[3][1] = fmaf(wv.w, xv.y, acc[3][1]);
      acc[3][2] = fmaf(wv.w, xv.z, acc[3][2]); acc[3][3] = fmaf(wv.w, xv.w, acc[3][3]);
    }
  }
#pragma unroll
  for (int i = 0; i < 4; ++i) {
    int o = o0 + to * 4 + i;
    float bv = bias[o];
    float4 r;
    r.x = acc[i][0] + bv; r.y = acc[i][1] + bv;
    r.z = acc[i][2] + bv; r.w = acc[i][3] + bv;
    *(float4*)&Y[((size_t)b * O + o) * 1024 + n0 + tn * 4] = r;
  }
}

// ---------------- squared norms over channels ----------------
__global__ __launch_bounds__(TPB) void sqnorm(
    const float* __restrict__ src, float* __restrict__ dst, int CC) {
  int i = blockIdx.x * TPB + threadIdx.x;  // B*N
  int b = i >> 10, n = i & 1023;
  const float* p = src + ((size_t)b * CC) * 1024 + n;
  float s = 0.f;
  for (int c = 0; c < CC; ++c) {
    float v = p[(size_t)c * 1024];
    s = fmaf(v, v, s);
  }
  dst[i] = s;
}

// ---------------- fused non-local attention, adds into out in-place ----------------
// grid (N/16, B), block 256. NT=16 query rows, MT=32 key tile.
__global__ __launch_bounds__(TPB) void attn_fused(
    const float* __restrict__ q, const float* __restrict__ k,
    const float* __restrict__ v, const float* __restrict__ q2g,
    const float* __restrict__ k2g, const float* __restrict__ sigp,
    float* __restrict__ out) {
  const int b = blockIdx.y, n0 = blockIdx.x * 16, tid = threadIdx.x;
  __shared__ float qs[16][132];
  __shared__ float ks[32][132];
  __shared__ float vs[256][32];
  __shared__ float ps[16][36];
  __shared__ float dsum[16], q2s[16], k2s[32];
  const float sg = *sigp;
  const float inv2s = 0.5f / (sg * sg);
  // stage q tile (transposed): qs[n][c]
  {
    int e = tid;
#pragma unroll
    for (int r = 0; r < 2; ++r, e += TPB) {
      int n4 = e & 3, c = e >> 2;
      float4 f = *(const float4*)&q[((size_t)b * 128 + c) * 1024 + n0 + n4 * 4];
      qs[n4 * 4 + 0][c] = f.x; qs[n4 * 4 + 1][c] = f.y;
      qs[n4 * 4 + 2][c] = f.z; qs[n4 * 4 + 3][c] = f.w;
    }
  }
  if (tid < 16) { dsum[tid] = 0.f; q2s[tid] = q2g[b * 1024 + n0 + tid]; }
  float acc[4][4] = {};
  const int n_s = tid >> 4, mq = tid & 15;
  const int naq = (tid >> 6) << 2;
  const int cq = tid & 63;
  for (int m0 = 0; m0 < 1024; m0 += 32) {
    __syncthreads();
    {  // stage k tile (transposed): ks[m][c]
      int e = tid;
#pragma unroll
      for (int r = 0; r < 4; ++r, e += TPB) {
        int m4 = e & 7, c = e >> 3;
        float4 f = *(const float4*)&k[((size_t)b * 128 + c) * 1024 + m0 + m4 * 4];
        ks[m4 * 4 + 0][c] = f.x; ks[m4 * 4 + 1][c] = f.y;
        ks[m4 * 4 + 2][c] = f.z; ks[m4 * 4 + 3][c] = f.w;
      }
      // stage v tile with XOR swizzle: vs[c][m ^ ((c&7)<<2)]
      e = tid;
#pragma unroll
      for (int r = 0; r < 8; ++r, e += TPB) {
        int m4 = e & 7, c = e >> 3;
        float4 f = *(const float4*)&v[((size_t)b * 256 + c) * 1024 + m0 + m4 * 4];
        *(float4*)&vs[c][(m4 * 4) ^ ((c & 7) << 2)] = f;
      }
      if (tid < 32) k2s[tid] = k2g[b * 1024 + m0 + tid];
    }
    __syncthreads();
    // similarity: each thread 1 row x 2 cols (m = mq + 16*mm)
    float dot[2] = {0.f, 0.f};
#pragma unroll
    for (int c4 = 0; c4 < 128; c4 += 4) {
      float4 qv = *(const float4*)&qs[n_s][c4];
#pragma unroll
      for (int mm = 0; mm < 2; ++mm) {
        float4 kv = *(const float4*)&ks[mq + 16 * mm][c4];
        dot[mm] = fmaf(qv.x, kv.x, dot[mm]);
        dot[mm] = fmaf(qv.y, kv.y, dot[mm]);
        dot[mm] = fmaf(qv.z, kv.z, dot[mm]);
        dot[mm] = fmaf(qv.w, kv.w, dot[mm]);
      }
    }
    float part = 0.f;
#pragma unroll
    for (int mm = 0; mm < 2; ++mm) {
      float d = q2s[n_s] + k2s[mq + 16 * mm] - 2.f * dot[mm];
      float sim = __expf(-d * inv2s);
      float p = __expf(sim);  // softmax over similarity, values in (1, e]
      ps[n_s][mq + 16 * mm] = p;
      part += p;
    }
    part += __shfl_xor(part, 1);
    part += __shfl_xor(part, 2);
    part += __shfl_xor(part, 4);
    part += __shfl_xor(part, 8);
    if (mq == 0) dsum[n_s] += part;
    __syncthreads();
    // AO accumulate: thread owns 4 rows (naq..naq+3) x 4 channels (cq+64j)
#pragma unroll
    for (int m4 = 0; m4 < 8; ++m4) {
      float4 pv[4];
#pragma unroll
      for (int i = 0; i < 4; ++i) pv[i] = *(const float4*)&ps[naq + i][m4 * 4];
#pragma unroll
      for (int j = 0; j < 4; ++j) {
        int c = cq + 64 * j;
        float4 vv = *(const float4*)&vs[c][(m4 * 4) ^ ((c & 7) << 2)];
#pragma unroll
        for (int i = 0; i < 4; ++i) {
          acc[i][j] = fmaf(pv[i].x, vv.x, acc[i][j]);
          acc[i][j] = fmaf(pv[i].y, vv.y, acc[i][j]);
          acc[i][j] = fmaf(pv[i].z, vv.z, acc[i][j]);
          acc[i][j] = fmaf(pv[i].w, vv.w, acc[i][j]);
        }
      }
    }
  }
  __syncthreads();
#pragma unroll
  for (int i = 0; i < 4; ++i) {
    float r = 1.f / dsum[naq + i];
#pragma unroll
    for (int j = 0; j < 4; ++j) {
      int c = cq + 64 * j;
      size_t idx = (size_t)b * 262144 + (size_t)(n0 + naq + i) * 256 + c;
      out[idx] += acc[i][j] * r;  // raw [B,N,C] -> [B,C,H,W] flat reinterpret
    }
  }
}

// ---------------- launcher ----------------
extern "C" void kernel_launch(void* const* d_in, const int* in_sizes, int n_in,
                              void* d_out, int out_size, void* d_ws, size_t ws_size,
                              hipStream_t stream) {
  (void)in_sizes; (void)n_in; (void)out_size; (void)ws_size;
  const float* x      = (const float*)d_in[0];
  const float* w1     = (const float*)d_in[1];
  const float* b1     = (const float*)d_in[2];
  const float* w3     = (const float*)d_in[3];
  const float* b3     = (const float*)d_in[4];
  const float* w5     = (const float*)d_in[5];
  const float* b5     = (const float*)d_in[6];
  const float* wq     = (const float*)d_in[7];
  const float* bq     = (const float*)d_in[8];
  const float* wk     = (const float*)d_in[9];
  const float* bk     = (const float*)d_in[10];
  const float* wv     = (const float*)d_in[11];
  const float* bv     = (const float*)d_in[12];
  const float* sigma  = (const float*)d_in[13];
  const float* ca_w1  = (const float*)d_in[14];
  const float* ca_w2  = (const float*)d_in[15];
  const float* sa_w   = (const float*)d_in[16];
  const float* tail_w = (const float*)d_in[17];
  const float* tail_b = (const float*)d_in[18];
  float* out_f = (float*)d_out;

  float* ws = (float*)d_ws;
  float* w_eff = ws;  ws += 1638400;
  float* b_eff = ws;  ws += 256;
  float* outb  = ws;  ws += 4194304;   // multi-scale conv result -> becomes non_local in place
  float* cbuf  = ws;  ws += 4194304;   // out*ca -> cbam_out in place
  float* qb    = ws;  ws += 2097152;
  float* kb    = ws;  ws += 2097152;
  float* vb    = ws;  ws += 4194304;
  float* avg   = ws;  ws += 4096;
  float* mxp   = ws;  ws += 4096;
  float* cab   = ws;  ws += 4096;
  float* sain  = ws;  ws += 32768;
  float* sab   = ws;  ws += 16384;
  float* q2b   = ws;  ws += 16384;
  float* k2b   = ws;  ws += 16384;

  // 1. merged conv weights + fused 5x5 conv
  hipLaunchKernelGGL(prep_weights, dim3(6400), dim3(TPB), 0, stream,
                     w1, b1, w3, b3, w5, b5, w_eff, b_eff);
  hipLaunchKernelGGL(conv5, dim3(16, 2, 16), dim3(TPB), 0, stream,
                     x, w_eff, b_eff, outb);
  // 2. CBAM
  hipLaunchKernelGGL(pool_avgmax, dim3(4096), dim3(TPB), 0, stream, outb, avg, mxp);
  hipLaunchKernelGGL(ca_mlp, dim3(16), dim3(TPB), 0, stream, avg, mxp, ca_w1, ca_w2, cab);
  hipLaunchKernelGGL(mul_ca, dim3(4096), dim3(TPB), 0, stream, outb, cab, cbuf);
  hipLaunchKernelGGL(spatial_pool, dim3(64), dim3(TPB), 0, stream, cbuf, sain);
  hipLaunchKernelGGL(sa_conv, dim3(64), dim3(TPB), 0, stream, sain, sa_w, sab);
  hipLaunchKernelGGL(mul_sa, dim3(4096), dim3(TPB), 0, stream, cbuf, sab);
  // 3. non-local attention
  hipLaunchKernelGGL(gemm1x1, dim3(16, 2, 16), dim3(TPB), 0, stream,
                     wq, bq, outb, outb, qb, 128, 256);
  hipLaunchKernelGGL(gemm1x1, dim3(16, 2, 16), dim3(TPB), 0, stream,
                     wk, bk, outb, outb, kb, 128, 256);
  hipLaunchKernelGGL(gemm1x1, dim3(16, 4, 16), dim3(TPB), 0, stream,
                     wv, bv, outb, outb, vb, 256, 256);
  hipLaunchKernelGGL(sqnorm, dim3(64), dim3(TPB), 0, stream, qb, q2b, 128);
  hipLaunchKernelGGL(sqnorm, dim3(64), dim3(TPB), 0, stream, kb, k2b, 128);
  hipLaunchKernelGGL(attn_fused, dim3(64, 16), dim3(TPB), 0, stream,
                     qb, kb, vb, q2b, k2b, sigma, outb);
  // 4. tail conv over concat [cbam_out, non_local]
  hipLaunchKernelGGL(gemm1x1, dim3(16, 4, 16), dim3(TPB), 0, stream,
                     tail_w, tail_b, cbuf, outb, out_f, 256, 512);
}

// Round 3
// 823.770 us; speedup vs baseline: 1.8482x; 1.8482x over previous
//
#include <hip/hip_runtime.h>
#include <cstddef>

#define TPB 256

typedef __bf16 bf16x8 __attribute__((ext_vector_type(8)));
typedef float f32x4 __attribute__((ext_vector_type(4)));
typedef unsigned short u16x8 __attribute__((ext_vector_type(8)));

__device__ __forceinline__ unsigned short f2bf(float f) {
  unsigned u = __float_as_uint(f);
  unsigned r = (u + 0x7FFFu + ((u >> 16) & 1u)) >> 16;
  return (unsigned short)r;
}
__device__ __forceinline__ float bf2f(unsigned short h) {
  return __uint_as_float(((unsigned)h) << 16);
}

// ---------------- P0: merged conv weights -> bf16 hi/lo in [tap][oc][c] ----------------
__global__ __launch_bounds__(TPB) void prep_w(
    const float* __restrict__ w1, const float* __restrict__ b1,
    const float* __restrict__ w3, const float* __restrict__ b3,
    const float* __restrict__ w5, const float* __restrict__ b5,
    unsigned short* __restrict__ wh, unsigned short* __restrict__ wl,
    float* __restrict__ b_eff) {
  int i = blockIdx.x * TPB + threadIdx.x;  // i < 25*65536
  int tap = i >> 16;
  int oc = (i >> 8) & 255;
  int c = i & 255;
  int kh = tap / 5, kw = tap - kh * 5;
  size_t occ = (size_t)((oc << 8) | c);
  float v = w5[occ * 25 + tap];
  if (kh >= 1 && kh <= 3 && kw >= 1 && kw <= 3)
    v += w3[occ * 9 + (kh - 1) * 3 + (kw - 1)];
  if (tap == 12) v += w1[occ];
  unsigned short h = f2bf(v);
  wh[i] = h;
  wl[i] = f2bf(v - bf2f(h));
  if (i < 256) b_eff[i] = b1[i] + b3[i] + b5[i];
}

// ---------------- P1: x fp32 NCHW -> bf16 hi/lo NHWC ----------------
__global__ __launch_bounds__(TPB) void prep_x(
    const float* __restrict__ x, unsigned short* __restrict__ xh,
    unsigned short* __restrict__ xl) {
  int i = blockIdx.x * TPB + threadIdx.x;  // < 16*32*1024
  int b = i >> 15, cg = (i >> 10) & 31, pix = i & 1023;
  u16x8 h8, l8;
#pragma unroll
  for (int j = 0; j < 8; ++j) {
    float v = x[((size_t)(b * 256 + cg * 8 + j)) * 1024 + pix];
    unsigned short h = f2bf(v);
    h8[j] = h;
    l8[j] = f2bf(v - bf2f(h));
  }
  size_t o = ((size_t)(b * 1024 + pix)) * 256 + cg * 8;
  *(u16x8*)(xh + o) = h8;
  *(u16x8*)(xl + o) = l8;
}

// ---------------- K1: fused 5x5 conv via bf16 MFMA implicit GEMM ----------------
// grid (8 row-tiles, 4 oc-tiles, 16 b), block 256 (4 waves).
// Block: 128 pixels (4 image rows; wave w -> row h0+w) x 64 oc. K loop: 8 c-chunks x 25 taps.
// LDS: x halo tile [8 rows][36 cols][40ch-pad] hi/lo + per-tap B [64oc][40ch-pad] hi/lo.
// pad-40 rows => ds_read_b128 slot = (5*idx+cg) mod 8: conflict-free.
__global__ __launch_bounds__(TPB) void conv5_mfma(
    const unsigned short* __restrict__ xh, const unsigned short* __restrict__ xl,
    const unsigned short* __restrict__ wh, const unsigned short* __restrict__ wl,
    const float* __restrict__ b_eff, float* __restrict__ out) {
  __shared__ unsigned short xsh[8 * 36 * 40], xsl[8 * 36 * 40];
  __shared__ unsigned short bsh[64 * 40], bsl[64 * 40];
  const int tid = threadIdx.x;
  const int h0 = blockIdx.x * 4;
  const int oc0 = blockIdx.y * 64;
  const int b = blockIdx.z;
  const int lane = tid & 63;
  const int wr = tid >> 6;  // wave -> image row h0+wr
  const int l15 = lane & 15, cg = lane >> 4;

  f32x4 acc[2][4];
#pragma unroll
  for (int mf = 0; mf < 2; ++mf)
#pragma unroll
    for (int nf = 0; nf < 4; ++nf)
#pragma unroll
      for (int r = 0; r < 4; ++r) acc[mf][nf][r] = 0.f;

  // A-frag lane base (elements): pixel col = mf*16 + l15, k-chunk = cg*8
  int abase[2];
  abase[0] = (wr * 36 + l15) * 40 + cg * 8;
  abase[1] = (wr * 36 + 16 + l15) * 40 + cg * 8;
  // B staging thread mapping
  const int p_oc = tid >> 2, p_cg = tid & 3;
  const int bs_o = p_oc * 40 + p_cg * 8;

  // prologue: stage B for (c0=0, tap=0)
  {
    size_t g = ((size_t)(oc0 + p_oc)) * 256 + p_cg * 8;
    *(uint4*)(bsh + bs_o) = *(const uint4*)(wh + g);
    *(uint4*)(bsl + bs_o) = *(const uint4*)(wl + g);
  }

  for (int c0 = 0; c0 < 256; c0 += 32) {
    // stage x halo tile (8 rows x 36 cols x 32 ch) hi/lo
#pragma unroll
    for (int it = 0; it < 5; ++it) {
      int idx = tid + it * TPB;
      if (idx < 1152) {
        int site = idx >> 2, scg = idx & 3;
        int row = site / 36, col = site - row * 36;
        int ih = h0 + row - 2, iw = col - 2;
        uint4 vh = {0u, 0u, 0u, 0u}, vl = {0u, 0u, 0u, 0u};
        if ((unsigned)ih < 32u && (unsigned)iw < 32u) {
          size_t g = ((size_t)(b * 1024 + ih * 32 + iw)) * 256 + c0 + scg * 8;
          vh = *(const uint4*)(xh + g);
          vl = *(const uint4*)(xl + g);
        }
        int o = site * 40 + scg * 8;
        *(uint4*)(xsh + o) = vh;
        *(uint4*)(xsl + o) = vl;
      }
    }
    __syncthreads();

    int aofs = 0, kwc = 0;
    for (int tap = 0; tap < 25; ++tap) {
      // prefetch next tap's B (global -> regs), hidden under MFMAs
      int ntap = tap + 1, nc0 = c0;
      if (ntap == 25) { ntap = 0; nc0 = c0 + 32; }
      const bool havenext = (nc0 < 256);
      uint4 nh = {0u, 0u, 0u, 0u}, nl = {0u, 0u, 0u, 0u};
      if (havenext) {
        size_t g = ((size_t)(ntap * 256 + oc0 + p_oc)) * 256 + nc0 + p_cg * 8;
        nh = *(const uint4*)(wh + g);
        nl = *(const uint4*)(wl + g);
      }
      // fragment loads
      bf16x8 Ah[2], Al[2], Bh[4], Bl[4];
#pragma unroll
      for (int mf = 0; mf < 2; ++mf) {
        Ah[mf] = *(const bf16x8*)(xsh + abase[mf] + aofs);
        Al[mf] = *(const bf16x8*)(xsl + abase[mf] + aofs);
      }
#pragma unroll
      for (int nf = 0; nf < 4; ++nf) {
        int o = nf * 16 * 40 + l15 * 40 + cg * 8;
        Bh[nf] = *(const bf16x8*)(bsh + o);
        Bl[nf] = *(const bf16x8*)(bsl + o);
      }
      // 3-pass split-precision MFMA
#pragma unroll
      for (int mf = 0; mf < 2; ++mf)
#pragma unroll
        for (int nf = 0; nf < 4; ++nf) {
          acc[mf][nf] = __builtin_amdgcn_mfma_f32_16x16x32_bf16(Ah[mf], Bh[nf], acc[mf][nf], 0, 0, 0);
          acc[mf][nf] = __builtin_amdgcn_mfma_f32_16x16x32_bf16(Ah[mf], Bl[nf], acc[mf][nf], 0, 0, 0);
          acc[mf][nf] = __builtin_amdgcn_mfma_f32_16x16x32_bf16(Al[mf], Bh[nf], acc[mf][nf], 0, 0, 0);
        }
      __syncthreads();  // all waves done reading current B
      if (havenext) {
        *(uint4*)(bsh + bs_o) = nh;
        *(uint4*)(bsl + bs_o) = nl;
      }
      __syncthreads();  // B writes visible
      // advance tap offset
      ++kwc;
      aofs += 40;
      if (kwc == 5) { kwc = 0; aofs += 31 * 40; }
    }
  }

  // epilogue: D layout col(oc)=lane&15, row(pixel)=cg*4+reg
#pragma unroll
  for (int mf = 0; mf < 2; ++mf)
#pragma unroll
    for (int nf = 0; nf < 4; ++nf) {
      int oc = oc0 + nf * 16 + l15;
      float bv = b_eff[oc];
      size_t base = ((size_t)(b * 256 + oc)) * 1024 + (h0 + wr) * 32 + mf * 16 + cg * 4;
      float4 r;
      r.x = acc[mf][nf][0] + bv;
      r.y = acc[mf][nf][1] + bv;
      r.z = acc[mf][nf][2] + bv;
      r.w = acc[mf][nf][3] + bv;
      *(float4*)(out + base) = r;
    }
}

// ---------------- K2: per-(b,c) avg+max pool ----------------
__global__ __launch_bounds__(TPB) void pool_avgmax(
    const float* __restrict__ out, float* __restrict__ avg, float* __restrict__ mx) {
  int bc = blockIdx.x;
  int tid = threadIdx.x;
  const float4 v = ((const float4*)(out + (size_t)bc * 1024))[tid];
  float s = v.x + v.y + v.z + v.w;
  float m = fmaxf(fmaxf(v.x, v.y), fmaxf(v.z, v.w));
#pragma unroll
  for (int off = 1; off < 64; off <<= 1) {
    s += __shfl_xor(s, off);
    m = fmaxf(m, __shfl_xor(m, off));
  }
  __shared__ float ss[4], ms[4];
  if ((tid & 63) == 0) { ss[tid >> 6] = s; ms[tid >> 6] = m; }
  __syncthreads();
  if (tid == 0) {
    s = ss[0] + ss[1] + ss[2] + ss[3];
    m = fmaxf(fmaxf(ms[0], ms[1]), fmaxf(ms[2], ms[3]));
    avg[bc] = s * (1.f / 1024.f);
    mx[bc] = m;
  }
}

// ---------------- K3: channel-attention MLP ----------------
__global__ __launch_bounds__(TPB) void ca_mlp(
    const float* __restrict__ avg, const float* __restrict__ mx,
    const float* __restrict__ w1, const float* __restrict__ w2,
    float* __restrict__ ca) {
  int b = blockIdx.x;
  int t = threadIdx.x;
  __shared__ float av[256], mv[256], h[16];
  av[t] = avg[b * 256 + t];
  mv[t] = mx[b * 256 + t];
  __syncthreads();
  if (t < 16) {
    float ha = 0.f, hm = 0.f;
    for (int c = 0; c < 256; ++c) {
      float wv = w1[t * 256 + c];
      ha += wv * av[c];
      hm += wv * mv[c];
    }
    h[t] = fmaxf(ha, 0.f) + fmaxf(hm, 0.f);
  }
  __syncthreads();
  float s = 0.f;
#pragma unroll
  for (int j = 0; j < 16; ++j) s += w2[t * 16 + j] * h[j];
  ca[b * 256 + t] = 1.f / (1.f + __expf(-s));
}

// ---------------- K4: c = out * ca ----------------
__global__ __launch_bounds__(TPB) void mul_ca(
    const float* __restrict__ out, const float* __restrict__ ca,
    float* __restrict__ cbuf) {
  int i = blockIdx.x * TPB + threadIdx.x;
  float4 v = ((const float4*)out)[i];
  float g = ca[i >> 8];
  v.x *= g; v.y *= g; v.z *= g; v.w *= g;
  ((float4*)cbuf)[i] = v;
}

// ---------------- K5: spatial mean/max over channels ----------------
__global__ __launch_bounds__(TPB) void spatial_pool(
    const float* __restrict__ cbuf, float* __restrict__ sa_in) {
  int i = blockIdx.x * TPB + threadIdx.x;
  int b = i >> 10, pix = i & 1023;
  const float* p = cbuf + (size_t)b * 262144 + pix;
  float s = 0.f, m = -3.4e38f;
  for (int ch = 0; ch < 256; ++ch) {
    float v = p[(size_t)ch * 1024];
    s += v;
    m = fmaxf(m, v);
  }
  sa_in[b * 2048 + pix] = s * (1.f / 256.f);
  sa_in[b * 2048 + 1024 + pix] = m;
}

// ---------------- K6: 7x7 spatial-attn conv + sigmoid ----------------
__global__ __launch_bounds__(TPB) void sa_conv(
    const float* __restrict__ sa_in, const float* __restrict__ sw,
    float* __restrict__ sa) {
  int i = blockIdx.x * TPB + threadIdx.x;
  int b = i >> 10, pix = i & 1023;
  int h = pix >> 5, w = pix & 31;
  float s = 0.f;
#pragma unroll
  for (int ci = 0; ci < 2; ++ci)
    for (int kh = 0; kh < 7; ++kh) {
      int ih = h + kh - 3;
      if ((unsigned)ih >= 32u) continue;
#pragma unroll
      for (int kw = 0; kw < 7; ++kw) {
        int iw = w + kw - 3;
        if ((unsigned)iw >= 32u) continue;
        s += sa_in[b * 2048 + ci * 1024 + ih * 32 + iw] * sw[ci * 49 + kh * 7 + kw];
      }
    }
  sa[i] = 1.f / (1.f + __expf(-s));
}

// ---------------- K7: cbam = c * sa ----------------
__global__ __launch_bounds__(TPB) void mul_sa(
    float* __restrict__ cbuf, const float* __restrict__ sa) {
  int i = blockIdx.x * TPB + threadIdx.x;
  int b = i >> 16;
  float4 g = ((const float4*)(sa + (size_t)b * 1024))[i & 255];
  float4 v = ((float4*)cbuf)[i];
  v.x *= g.x; v.y *= g.y; v.z *= g.z; v.w *= g.w;
  ((float4*)cbuf)[i] = v;
}

// ---------------- GEMM: Y[b][o][n] = bias[o] + sum_k W[o,k] * X[b,k,n] ----------------
__global__ __launch_bounds__(TPB) void gemm1x1(
    const float* __restrict__ Wm, const float* __restrict__ bias,
    const float* __restrict__ Xa, const float* __restrict__ Xb,
    float* __restrict__ Y, int O, int K) {
  int tid = threadIdx.x;
  int n0 = blockIdx.x * 64, o0 = blockIdx.y * 64, b = blockIdx.z;
  __shared__ float Ws[16][68];
  __shared__ float Xs[16][64];
  float acc[4][4] = {};
  int to = tid & 15, tn = tid >> 4;
  for (int k0 = 0; k0 < K; k0 += 16) {
    const float* Xp = Xa;
    int kof = k0;
    if (k0 >= 256) { Xp = Xb; kof = k0 - 256; }
    __syncthreads();
    {
      int e = tid;
#pragma unroll
      for (int r = 0; r < 4; ++r, e += TPB) {
        int kk = e & 15, o = e >> 4;
        Ws[kk][o] = Wm[(size_t)(o0 + o) * K + k0 + kk];
      }
      e = tid;
#pragma unroll
      for (int r = 0; r < 4; ++r, e += TPB) {
        int nn = e & 63, kk = e >> 6;
        Xs[kk][nn] = Xp[((size_t)b * 256 + kof + kk) * 1024 + n0 + nn];
      }
    }
    __syncthreads();
#pragma unroll
    for (int kk = 0; kk < 16; ++kk) {
      float4 wv = *(const float4*)&Ws[kk][to * 4];
      float4 xv = *(const float4*)&Xs[kk][tn * 4];
      acc[0][0] = fmaf(wv.x, xv.x, acc[0][0]); acc[0][1] = fmaf(wv.x, xv.y, acc[0][1]);
      acc[0][2] = fmaf(wv.x, xv.z, acc[0][2]); acc[0][3] = fmaf(wv.x, xv.w, acc[0][3]);
      acc[1][0] = fmaf(wv.y, xv.x, acc[1][0]); acc[1][1] = fmaf(wv.y, xv.y, acc[1][1]);
      acc[1][2] = fmaf(wv.y, xv.z, acc[1][2]); acc[1][3] = fmaf(wv.y, xv.w, acc[1][3]);
      acc[2][0] = fmaf(wv.z, xv.x, acc[2][0]); acc[2][1] = fmaf(wv.z, xv.y, acc[2][1]);
      acc[2][2] = fmaf(wv.z, xv.z, acc[2][2]); acc[2][3] = fmaf(wv.z, xv.w, acc[2][3]);
      acc[3][0] = fmaf(wv.w, xv.x, acc[3][0]); acc[3][1] = fmaf(wv.w, xv.y, acc[3][1]);
      acc[3][2] = fmaf(wv.w, xv.z, acc[3][2]); acc[3][3] = fmaf(wv.w, xv.w, acc[3][3]);
    }
  }
#pragma unroll
  for (int i = 0; i < 4; ++i) {
    int o = o0 + to * 4 + i;
    float bv = bias[o];
    float4 r;
    r.x = acc[i][0] + bv; r.y = acc[i][1] + bv;
    r.z = acc[i][2] + bv; r.w = acc[i][3] + bv;
    *(float4*)&Y[((size_t)b * O + o) * 1024 + n0 + tn * 4] = r;
  }
}

// ---------------- squared norms over channels ----------------
__global__ __launch_bounds__(TPB) void sqnorm(
    const float* __restrict__ src, float* __restrict__ dst, int CC) {
  int i = blockIdx.x * TPB + threadIdx.x;
  int b = i >> 10, n = i & 1023;
  const float* p = src + ((size_t)b * CC) * 1024 + n;
  float s = 0.f;
  for (int c = 0; c < CC; ++c) {
    float v = p[(size_t)c * 1024];
    s = fmaf(v, v, s);
  }
  dst[i] = s;
}

// ---------------- fused non-local attention, adds into out in-place ----------------
__global__ __launch_bounds__(TPB) void attn_fused(
    const float* __restrict__ q, const float* __restrict__ k,
    const float* __restrict__ v, const float* __restrict__ q2g,
    const float* __restrict__ k2g, const float* __restrict__ sigp,
    float* __restrict__ out) {
  const int b = blockIdx.y, n0 = blockIdx.x * 16, tid = threadIdx.x;
  __shared__ float qs[16][132];
  __shared__ float ks[32][132];
  __shared__ float vs[256][32];
  __shared__ float ps[16][36];
  __shared__ float dsum[16], q2s[16], k2s[32];
  const float sg = *sigp;
  const float inv2s = 0.5f / (sg * sg);
  {
    int e = tid;
#pragma unroll
    for (int r = 0; r < 2; ++r, e += TPB) {
      int n4 = e & 3, c = e >> 2;
      float4 f = *(const float4*)&q[((size_t)b * 128 + c) * 1024 + n0 + n4 * 4];
      qs[n4 * 4 + 0][c] = f.x; qs[n4 * 4 + 1][c] = f.y;
      qs[n4 * 4 + 2][c] = f.z; qs[n4 * 4 + 3][c] = f.w;
    }
  }
  if (tid < 16) { dsum[tid] = 0.f; q2s[tid] = q2g[b * 1024 + n0 + tid]; }
  float acc[4][4] = {};
  const int n_s = tid >> 4, mq = tid & 15;
  const int naq = (tid >> 6) << 2;
  const int cq = tid & 63;
  for (int m0 = 0; m0 < 1024; m0 += 32) {
    __syncthreads();
    {
      int e = tid;
#pragma unroll
      for (int r = 0; r < 4; ++r, e += TPB) {
        int m4 = e & 7, c = e >> 3;
        float4 f = *(const float4*)&k[((size_t)b * 128 + c) * 1024 + m0 + m4 * 4];
        ks[m4 * 4 + 0][c] = f.x; ks[m4 * 4 + 1][c] = f.y;
        ks[m4 * 4 + 2][c] = f.z; ks[m4 * 4 + 3][c] = f.w;
      }
      e = tid;
#pragma unroll
      for (int r = 0; r < 8; ++r, e += TPB) {
        int m4 = e & 7, c = e >> 3;
        float4 f = *(const float4*)&v[((size_t)b * 256 + c) * 1024 + m0 + m4 * 4];
        *(float4*)&vs[c][(m4 * 4) ^ ((c & 7) << 2)] = f;
      }
      if (tid < 32) k2s[tid] = k2g[b * 1024 + m0 + tid];
    }
    __syncthreads();
    float dot[2] = {0.f, 0.f};
#pragma unroll
    for (int c4 = 0; c4 < 128; c4 += 4) {
      float4 qv = *(const float4*)&qs[n_s][c4];
#pragma unroll
      for (int mm = 0; mm < 2; ++mm) {
        float4 kv = *(const float4*)&ks[mq + 16 * mm][c4];
        dot[mm] = fmaf(qv.x, kv.x, dot[mm]);
        dot[mm] = fmaf(qv.y, kv.y, dot[mm]);
        dot[mm] = fmaf(qv.z, kv.z, dot[mm]);
        dot[mm] = fmaf(qv.w, kv.w, dot[mm]);
      }
    }
    float part = 0.f;
#pragma unroll
    for (int mm = 0; mm < 2; ++mm) {
      float d = q2s[n_s] + k2s[mq + 16 * mm] - 2.f * dot[mm];
      float sim = __expf(-d * inv2s);
      float p = __expf(sim);
      ps[n_s][mq + 16 * mm] = p;
      part += p;
    }
    part += __shfl_xor(part, 1);
    part += __shfl_xor(part, 2);
    part += __shfl_xor(part, 4);
    part += __shfl_xor(part, 8);
    if (mq == 0) dsum[n_s] += part;
    __syncthreads();
#pragma unroll
    for (int m4 = 0; m4 < 8; ++m4) {
      float4 pv[4];
#pragma unroll
      for (int i = 0; i < 4; ++i) pv[i] = *(const float4*)&ps[naq + i][m4 * 4];
#pragma unroll
      for (int j = 0; j < 4; ++j) {
        int c = cq + 64 * j;
        float4 vv = *(const float4*)&vs[c][(m4 * 4) ^ ((c & 7) << 2)];
#pragma unroll
        for (int i = 0; i < 4; ++i) {
          acc[i][j] = fmaf(pv[i].x, vv.x, acc[i][j]);
          acc[i][j] = fmaf(pv[i].y, vv.y, acc[i][j]);
          acc[i][j] = fmaf(pv[i].z, vv.z, acc[i][j]);
          acc[i][j] = fmaf(pv[i].w, vv.w, acc[i][j]);
        }
      }
    }
  }
  __syncthreads();
#pragma unroll
  for (int i = 0; i < 4; ++i) {
    float r = 1.f / dsum[naq + i];
#pragma unroll
    for (int j = 0; j < 4; ++j) {
      int c = cq + 64 * j;
      size_t idx = (size_t)b * 262144 + (size_t)(n0 + naq + i) * 256 + c;
      out[idx] += acc[i][j] * r;
    }
  }
}

// ---------------- launcher ----------------
extern "C" void kernel_launch(void* const* d_in, const int* in_sizes, int n_in,
                              void* d_out, int out_size, void* d_ws, size_t ws_size,
                              hipStream_t stream) {
  (void)in_sizes; (void)n_in; (void)out_size; (void)ws_size;
  const float* x      = (const float*)d_in[0];
  const float* w1     = (const float*)d_in[1];
  const float* b1     = (const float*)d_in[2];
  const float* w3     = (const float*)d_in[3];
  const float* b3     = (const float*)d_in[4];
  const float* w5     = (const float*)d_in[5];
  const float* b5     = (const float*)d_in[6];
  const float* wq     = (const float*)d_in[7];
  const float* bq     = (const float*)d_in[8];
  const float* wk     = (const float*)d_in[9];
  const float* bk     = (const float*)d_in[10];
  const float* wv     = (const float*)d_in[11];
  const float* bv     = (const float*)d_in[12];
  const float* sigma  = (const float*)d_in[13];
  const float* ca_w1  = (const float*)d_in[14];
  const float* ca_w2  = (const float*)d_in[15];
  const float* sa_w   = (const float*)d_in[16];
  const float* tail_w = (const float*)d_in[17];
  const float* tail_b = (const float*)d_in[18];
  float* out_f = (float*)d_out;

  float* ws = (float*)d_ws;
  float* outb  = ws;  ws += 4194304;
  float* cbuf  = ws;  ws += 4194304;
  float* qb    = ws;  ws += 2097152;
  float* kb    = ws;  ws += 2097152;
  float* vb    = ws;  ws += 4194304;
  float* b_eff = ws;  ws += 256;
  float* avg   = ws;  ws += 4096;
  float* mxp   = ws;  ws += 4096;
  float* cab   = ws;  ws += 4096;
  float* sain  = ws;  ws += 32768;
  float* sab   = ws;  ws += 16384;
  float* q2b   = ws;  ws += 16384;
  float* k2b   = ws;  ws += 16384;
  unsigned short* us = (unsigned short*)ws;
  unsigned short* wfh = us;  us += 1638400;
  unsigned short* wfl = us;  us += 1638400;
  unsigned short* xhb = us;  us += 4194304;
  unsigned short* xlb = us;  us += 4194304;

  // 1. prep + fused 5x5 conv (bf16 MFMA, 3-pass split precision)
  hipLaunchKernelGGL(prep_w, dim3(6400), dim3(TPB), 0, stream,
                     w1, b1, w3, b3, w5, b5, wfh, wfl, b_eff);
  hipLaunchKernelGGL(prep_x, dim3(2048), dim3(TPB), 0, stream, x, xhb, xlb);
  hipLaunchKernelGGL(conv5_mfma, dim3(8, 4, 16), dim3(TPB), 0, stream,
                     xhb, xlb, wfh, wfl, b_eff, outb);
  // 2. CBAM
  hipLaunchKernelGGL(pool_avgmax, dim3(4096), dim3(TPB), 0, stream, outb, avg, mxp);
  hipLaunchKernelGGL(ca_mlp, dim3(16), dim3(TPB), 0, stream, avg, mxp, ca_w1, ca_w2, cab);
  hipLaunchKernelGGL(mul_ca, dim3(4096), dim3(TPB), 0, stream, outb, cab, cbuf);
  hipLaunchKernelGGL(spatial_pool, dim3(64), dim3(TPB), 0, stream, cbuf, sain);
  hipLaunchKernelGGL(sa_conv, dim3(64), dim3(TPB), 0, stream, sain, sa_w, sab);
  hipLaunchKernelGGL(mul_sa, dim3(4096), dim3(TPB), 0, stream, cbuf, sab);
  // 3. non-local attention
  hipLaunchKernelGGL(gemm1x1, dim3(16, 2, 16), dim3(TPB), 0, stream,
                     wq, bq, outb, outb, qb, 128, 256);
  hipLaunchKernelGGL(gemm1x1, dim3(16, 2, 16), dim3(TPB), 0, stream,
                     wk, bk, outb, outb, kb, 128, 256);
  hipLaunchKernelGGL(gemm1x1, dim3(16, 4, 16), dim3(TPB), 0, stream,
                     wv, bv, outb, outb, vb, 256, 256);
  hipLaunchKernelGGL(sqnorm, dim3(64), dim3(TPB), 0, stream, qb, q2b, 128);
  hipLaunchKernelGGL(sqnorm, dim3(64), dim3(TPB), 0, stream, kb, k2b, 128);
  hipLaunchKernelGGL(attn_fused, dim3(64, 16), dim3(TPB), 0, stream,
                     qb, kb, vb, q2b, k2b, sigma, outb);
  // 4. tail conv over concat [cbam_out, non_local]
  hipLaunchKernelGGL(gemm1x1, dim3(16, 4, 16), dim3(TPB), 0, stream,
                     tail_w, tail_b, cbuf, outb, out_f, 256, 512);
}

// Round 5
// 652.546 us; speedup vs baseline: 2.3332x; 1.2624x over previous
//
#include <hip/hip_runtime.h>
#include <cstddef>

#define TPB 256

typedef __bf16 bf16x8 __attribute__((ext_vector_type(8)));
typedef float f32x4 __attribute__((ext_vector_type(4)));
typedef unsigned short u16x8 __attribute__((ext_vector_type(8)));

__device__ __forceinline__ unsigned short f2bf(float f) {
  unsigned u = __float_as_uint(f);
  unsigned r = (u + 0x7FFFu + ((u >> 16) & 1u)) >> 16;
  return (unsigned short)r;
}
__device__ __forceinline__ float bf2f(unsigned short h) {
  return __uint_as_float(((unsigned)h) << 16);
}

// ---------------- P0: merged conv weights -> bf16 hi/lo in [tap][oc][c] ----------------
__global__ __launch_bounds__(TPB) void prep_w(
    const float* __restrict__ w1, const float* __restrict__ b1,
    const float* __restrict__ w3, const float* __restrict__ b3,
    const float* __restrict__ w5, const float* __restrict__ b5,
    unsigned short* __restrict__ wh, unsigned short* __restrict__ wl,
    float* __restrict__ b_eff) {
  int i = blockIdx.x * TPB + threadIdx.x;  // i < 25*65536
  int tap = i >> 16;
  int oc = (i >> 8) & 255;
  int c = i & 255;
  int kh = tap / 5, kw = tap - kh * 5;
  size_t occ = (size_t)((oc << 8) | c);
  float v = w5[occ * 25 + tap];
  if (kh >= 1 && kh <= 3 && kw >= 1 && kw <= 3)
    v += w3[occ * 9 + (kh - 1) * 3 + (kw - 1)];
  if (tap == 12) v += w1[occ];
  unsigned short h = f2bf(v);
  wh[i] = h;
  wl[i] = f2bf(v - bf2f(h));
  if (i < 256) b_eff[i] = b1[i] + b3[i] + b5[i];
}

// ---------------- P1: x fp32 NCHW -> bf16 hi/lo NHWC ----------------
__global__ __launch_bounds__(TPB) void prep_x(
    const float* __restrict__ x, unsigned short* __restrict__ xh,
    unsigned short* __restrict__ xl) {
  int i = blockIdx.x * TPB + threadIdx.x;  // < 16*32*1024
  int b = i >> 15, cg = (i >> 10) & 31, pix = i & 1023;
  u16x8 h8, l8;
#pragma unroll
  for (int j = 0; j < 8; ++j) {
    float v = x[((size_t)(b * 256 + cg * 8 + j)) * 1024 + pix];
    unsigned short h = f2bf(v);
    h8[j] = h;
    l8[j] = f2bf(v - bf2f(h));
  }
  size_t o = ((size_t)(b * 1024 + pix)) * 256 + cg * 8;
  *(u16x8*)(xh + o) = h8;
  *(u16x8*)(xl + o) = l8;
}

// ---------------- K1: fused 5x5 conv via bf16 MFMA implicit GEMM ----------------
__global__ __launch_bounds__(TPB) void conv5_mfma(
    const unsigned short* __restrict__ xh, const unsigned short* __restrict__ xl,
    const unsigned short* __restrict__ wh, const unsigned short* __restrict__ wl,
    const float* __restrict__ b_eff, float* __restrict__ out) {
  __shared__ unsigned short xsh[8 * 36 * 40], xsl[8 * 36 * 40];
  __shared__ unsigned short bsh[64 * 40], bsl[64 * 40];
  const int tid = threadIdx.x;
  const int h0 = blockIdx.x * 4;
  const int oc0 = blockIdx.y * 64;
  const int b = blockIdx.z;
  const int lane = tid & 63;
  const int wr = tid >> 6;
  const int l15 = lane & 15, cg = lane >> 4;

  f32x4 acc[2][4];
#pragma unroll
  for (int mf = 0; mf < 2; ++mf)
#pragma unroll
    for (int nf = 0; nf < 4; ++nf)
#pragma unroll
      for (int r = 0; r < 4; ++r) acc[mf][nf][r] = 0.f;

  int abase[2];
  abase[0] = (wr * 36 + l15) * 40 + cg * 8;
  abase[1] = (wr * 36 + 16 + l15) * 40 + cg * 8;
  const int p_oc = tid >> 2, p_cg = tid & 3;
  const int bs_o = p_oc * 40 + p_cg * 8;

  {
    size_t g = ((size_t)(oc0 + p_oc)) * 256 + p_cg * 8;
    *(uint4*)(bsh + bs_o) = *(const uint4*)(wh + g);
    *(uint4*)(bsl + bs_o) = *(const uint4*)(wl + g);
  }

  for (int c0 = 0; c0 < 256; c0 += 32) {
#pragma unroll
    for (int it = 0; it < 5; ++it) {
      int idx = tid + it * TPB;
      if (idx < 1152) {
        int site = idx >> 2, scg = idx & 3;
        int row = site / 36, col = site - row * 36;
        int ih = h0 + row - 2, iw = col - 2;
        uint4 vh = {0u, 0u, 0u, 0u}, vl = {0u, 0u, 0u, 0u};
        if ((unsigned)ih < 32u && (unsigned)iw < 32u) {
          size_t g = ((size_t)(b * 1024 + ih * 32 + iw)) * 256 + c0 + scg * 8;
          vh = *(const uint4*)(xh + g);
          vl = *(const uint4*)(xl + g);
        }
        int o = site * 40 + scg * 8;
        *(uint4*)(xsh + o) = vh;
        *(uint4*)(xsl + o) = vl;
      }
    }
    __syncthreads();

    int aofs = 0, kwc = 0;
    for (int tap = 0; tap < 25; ++tap) {
      int ntap = tap + 1, nc0 = c0;
      if (ntap == 25) { ntap = 0; nc0 = c0 + 32; }
      const bool havenext = (nc0 < 256);
      uint4 nh = {0u, 0u, 0u, 0u}, nl = {0u, 0u, 0u, 0u};
      if (havenext) {
        size_t g = ((size_t)(ntap * 256 + oc0 + p_oc)) * 256 + nc0 + p_cg * 8;
        nh = *(const uint4*)(wh + g);
        nl = *(const uint4*)(wl + g);
      }
      bf16x8 Ah[2], Al[2], Bh[4], Bl[4];
#pragma unroll
      for (int mf = 0; mf < 2; ++mf) {
        Ah[mf] = *(const bf16x8*)(xsh + abase[mf] + aofs);
        Al[mf] = *(const bf16x8*)(xsl + abase[mf] + aofs);
      }
#pragma unroll
      for (int nf = 0; nf < 4; ++nf) {
        int o = nf * 16 * 40 + l15 * 40 + cg * 8;
        Bh[nf] = *(const bf16x8*)(bsh + o);
        Bl[nf] = *(const bf16x8*)(bsl + o);
      }
#pragma unroll
      for (int mf = 0; mf < 2; ++mf)
#pragma unroll
        for (int nf = 0; nf < 4; ++nf) {
          acc[mf][nf] = __builtin_amdgcn_mfma_f32_16x16x32_bf16(Ah[mf], Bh[nf], acc[mf][nf], 0, 0, 0);
          acc[mf][nf] = __builtin_amdgcn_mfma_f32_16x16x32_bf16(Ah[mf], Bl[nf], acc[mf][nf], 0, 0, 0);
          acc[mf][nf] = __builtin_amdgcn_mfma_f32_16x16x32_bf16(Al[mf], Bh[nf], acc[mf][nf], 0, 0, 0);
        }
      __syncthreads();
      if (havenext) {
        *(uint4*)(bsh + bs_o) = nh;
        *(uint4*)(bsl + bs_o) = nl;
      }
      __syncthreads();
      ++kwc;
      aofs += 40;
      if (kwc == 5) { kwc = 0; aofs += 31 * 40; }
    }
  }

#pragma unroll
  for (int mf = 0; mf < 2; ++mf)
#pragma unroll
    for (int nf = 0; nf < 4; ++nf) {
      int oc = oc0 + nf * 16 + l15;
      float bv = b_eff[oc];
      size_t base = ((size_t)(b * 256 + oc)) * 1024 + (h0 + wr) * 32 + mf * 16 + cg * 4;
      float4 r;
      r.x = acc[mf][nf][0] + bv;
      r.y = acc[mf][nf][1] + bv;
      r.z = acc[mf][nf][2] + bv;
      r.w = acc[mf][nf][3] + bv;
      *(float4*)(out + base) = r;
    }
}

// ---------------- K2: per-(b,c) avg+max pool ----------------
__global__ __launch_bounds__(TPB) void pool_avgmax(
    const float* __restrict__ out, float* __restrict__ avg, float* __restrict__ mx) {
  int bc = blockIdx.x;
  int tid = threadIdx.x;
  const float4 v = ((const float4*)(out + (size_t)bc * 1024))[tid];
  float s = v.x + v.y + v.z + v.w;
  float m = fmaxf(fmaxf(v.x, v.y), fmaxf(v.z, v.w));
#pragma unroll
  for (int off = 1; off < 64; off <<= 1) {
    s += __shfl_xor(s, off);
    m = fmaxf(m, __shfl_xor(m, off));
  }
  __shared__ float ss[4], ms[4];
  if ((tid & 63) == 0) { ss[tid >> 6] = s; ms[tid >> 6] = m; }
  __syncthreads();
  if (tid == 0) {
    s = ss[0] + ss[1] + ss[2] + ss[3];
    m = fmaxf(fmaxf(ms[0], ms[1]), fmaxf(ms[2], ms[3]));
    avg[bc] = s * (1.f / 1024.f);
    mx[bc] = m;
  }
}

// ---------------- K3: channel-attention MLP ----------------
__global__ __launch_bounds__(TPB) void ca_mlp(
    const float* __restrict__ avg, const float* __restrict__ mx,
    const float* __restrict__ w1, const float* __restrict__ w2,
    float* __restrict__ ca) {
  int b = blockIdx.x;
  int t = threadIdx.x;
  __shared__ float av[256], mv[256], h[16];
  av[t] = avg[b * 256 + t];
  mv[t] = mx[b * 256 + t];
  __syncthreads();
  if (t < 16) {
    float ha = 0.f, hm = 0.f;
    for (int c = 0; c < 256; ++c) {
      float wv = w1[t * 256 + c];
      ha += wv * av[c];
      hm += wv * mv[c];
    }
    h[t] = fmaxf(ha, 0.f) + fmaxf(hm, 0.f);
  }
  __syncthreads();
  float s = 0.f;
#pragma unroll
  for (int j = 0; j < 16; ++j) s += w2[t * 16 + j] * h[j];
  ca[b * 256 + t] = 1.f / (1.f + __expf(-s));
}

// ---------------- K4: c = out * ca ----------------
__global__ __launch_bounds__(TPB) void mul_ca(
    const float* __restrict__ out, const float* __restrict__ ca,
    float* __restrict__ cbuf) {
  int i = blockIdx.x * TPB + threadIdx.x;
  float4 v = ((const float4*)out)[i];
  float g = ca[i >> 8];
  v.x *= g; v.y *= g; v.z *= g; v.w *= g;
  ((float4*)cbuf)[i] = v;
}

// ---------------- K5: spatial mean/max over channels ----------------
__global__ __launch_bounds__(TPB) void spatial_pool(
    const float* __restrict__ cbuf, float* __restrict__ sa_in) {
  int i = blockIdx.x * TPB + threadIdx.x;
  int b = i >> 10, pix = i & 1023;
  const float* p = cbuf + (size_t)b * 262144 + pix;
  float s = 0.f, m = -3.4e38f;
  for (int ch = 0; ch < 256; ++ch) {
    float v = p[(size_t)ch * 1024];
    s += v;
    m = fmaxf(m, v);
  }
  sa_in[b * 2048 + pix] = s * (1.f / 256.f);
  sa_in[b * 2048 + 1024 + pix] = m;
}

// ---------------- K6: 7x7 spatial-attn conv + sigmoid ----------------
__global__ __launch_bounds__(TPB) void sa_conv(
    const float* __restrict__ sa_in, const float* __restrict__ sw,
    float* __restrict__ sa) {
  int i = blockIdx.x * TPB + threadIdx.x;
  int b = i >> 10, pix = i & 1023;
  int h = pix >> 5, w = pix & 31;
  float s = 0.f;
#pragma unroll
  for (int ci = 0; ci < 2; ++ci)
    for (int kh = 0; kh < 7; ++kh) {
      int ih = h + kh - 3;
      if ((unsigned)ih >= 32u) continue;
#pragma unroll
      for (int kw = 0; kw < 7; ++kw) {
        int iw = w + kw - 3;
        if ((unsigned)iw >= 32u) continue;
        s += sa_in[b * 2048 + ci * 1024 + ih * 32 + iw] * sw[ci * 49 + kh * 7 + kw];
      }
    }
  sa[i] = 1.f / (1.f + __expf(-s));
}

// ---------------- K7: cbam = c * sa ----------------
__global__ __launch_bounds__(TPB) void mul_sa(
    float* __restrict__ cbuf, const float* __restrict__ sa) {
  int i = blockIdx.x * TPB + threadIdx.x;
  int b = i >> 16;
  float4 g = ((const float4*)(sa + (size_t)b * 1024))[i & 255];
  float4 v = ((float4*)cbuf)[i];
  v.x *= g.x; v.y *= g.y; v.z *= g.z; v.w *= g.w;
  ((float4*)cbuf)[i] = v;
}

// ---------------- GEMM: Y[b][o][n] = bias[o] + sum_k W[o,k] * X[b,k,n] ----------------
__global__ __launch_bounds__(TPB) void gemm1x1(
    const float* __restrict__ Wm, const float* __restrict__ bias,
    const float* __restrict__ Xa, const float* __restrict__ Xb,
    float* __restrict__ Y, int O, int K) {
  int tid = threadIdx.x;
  int n0 = blockIdx.x * 64, o0 = blockIdx.y * 64, b = blockIdx.z;
  __shared__ float Ws[16][68];
  __shared__ float Xs[16][64];
  float acc[4][4] = {};
  int to = tid & 15, tn = tid >> 4;
  for (int k0 = 0; k0 < K; k0 += 16) {
    const float* Xp = Xa;
    int kof = k0;
    if (k0 >= 256) { Xp = Xb; kof = k0 - 256; }
    __syncthreads();
    {
      int e = tid;
#pragma unroll
      for (int r = 0; r < 4; ++r, e += TPB) {
        int kk = e & 15, o = e >> 4;
        Ws[kk][o] = Wm[(size_t)(o0 + o) * K + k0 + kk];
      }
      e = tid;
#pragma unroll
      for (int r = 0; r < 4; ++r, e += TPB) {
        int nn = e & 63, kk = e >> 6;
        Xs[kk][nn] = Xp[((size_t)b * 256 + kof + kk) * 1024 + n0 + nn];
      }
    }
    __syncthreads();
#pragma unroll
    for (int kk = 0; kk < 16; ++kk) {
      float4 wv = *(const float4*)&Ws[kk][to * 4];
      float4 xv = *(const float4*)&Xs[kk][tn * 4];
      acc[0][0] = fmaf(wv.x, xv.x, acc[0][0]); acc[0][1] = fmaf(wv.x, xv.y, acc[0][1]);
      acc[0][2] = fmaf(wv.x, xv.z, acc[0][2]); acc[0][3] = fmaf(wv.x, xv.w, acc[0][3]);
      acc[1][0] = fmaf(wv.y, xv.x, acc[1][0]); acc[1][1] = fmaf(wv.y, xv.y, acc[1][1]);
      acc[1][2] = fmaf(wv.y, xv.z, acc[1][2]); acc[1][3] = fmaf(wv.y, xv.w, acc[1][3]);
      acc[2][0] = fmaf(wv.z, xv.x, acc[2][0]); acc[2][1] = fmaf(wv.z, xv.y, acc[2][1]);
      acc[2][2] = fmaf(wv.z, xv.z, acc[2][2]); acc[2][3] = fmaf(wv.z, xv.w, acc[2][3]);
      acc[3][0] = fmaf(wv.w, xv.x, acc[3][0]); acc[3][1] = fmaf(wv.w, xv.y, acc[3][1]);
      acc[3][2] = fmaf(wv.w, xv.z, acc[3][2]); acc[3][3] = fmaf(wv.w, xv.w, acc[3][3]);
    }
  }
#pragma unroll
  for (int i = 0; i < 4; ++i) {
    int o = o0 + to * 4 + i;
    float bv = bias[o];
    float4 r;
    r.x = acc[i][0] + bv; r.y = acc[i][1] + bv;
    r.z = acc[i][2] + bv; r.w = acc[i][3] + bv;
    *(float4*)&Y[((size_t)b * O + o) * 1024 + n0 + tn * 4] = r;
  }
}

// ---------------- squared norms over channels ----------------
__global__ __launch_bounds__(TPB) void sqnorm(
    const float* __restrict__ src, float* __restrict__ dst, int CC) {
  int i = blockIdx.x * TPB + threadIdx.x;
  int b = i >> 10, n = i & 1023;
  const float* p = src + ((size_t)b * CC) * 1024 + n;
  float s = 0.f;
  for (int c = 0; c < CC; ++c) {
    float v = p[(size_t)c * 1024];
    s = fmaf(v, v, s);
  }
  dst[i] = s;
}

// ---------------- transpose+split: fp32 [b][128][1024] -> bf16 hi/lo [b][1024][128], rows XOR-swizzled ----------------
__global__ __launch_bounds__(TPB) void xpose_qk(
    const float* __restrict__ X, unsigned short* __restrict__ H,
    unsigned short* __restrict__ L) {
  __shared__ float xs[64 * 132];
  const int tid = threadIdx.x;
  const int n0 = blockIdx.x * 64, b = blockIdx.y;
#pragma unroll
  for (int i = 0; i < 8; ++i) {
    int idx = tid + i * TPB;  // 2048 float4 tasks: 128 c-rows x 16 n-quads
    int c = idx >> 4, nq = idx & 15;
    float4 f = *(const float4*)&X[((size_t)(b * 128 + c)) * 1024 + n0 + nq * 4];
    xs[(nq * 4 + 0) * 132 + c] = f.x;
    xs[(nq * 4 + 1) * 132 + c] = f.y;
    xs[(nq * 4 + 2) * 132 + c] = f.z;
    xs[(nq * 4 + 3) * 132 + c] = f.w;
  }
  __syncthreads();
#pragma unroll
  for (int i = 0; i < 4; ++i) {
    int idx = tid + i * TPB;  // 1024 tasks: 64 n x 16 c-octets
    int n = idx >> 4, oct = idx & 15;
    u16x8 h8, l8;
#pragma unroll
    for (int j = 0; j < 8; ++j) {
      float v = xs[n * 132 + oct * 8 + j];
      unsigned short h = f2bf(v);
      h8[j] = h;
      l8[j] = f2bf(v - bf2f(h));
    }
    int byteoff = (oct * 16) ^ ((n & 7) << 4);
    size_t rowbase = ((size_t)(b * 1024 + n0 + n)) * 256;  // bytes
    *(u16x8*)((char*)H + rowbase + byteoff) = h8;
    *(u16x8*)((char*)L + rowbase + byteoff) = l8;
  }
}

// ---------------- V convert: fp32 [b][256][1024] -> bf16 same layout, 128B-chunk swizzled by row ----------------
__global__ __launch_bounds__(TPB) void conv_v(
    const float* __restrict__ V, unsigned short* __restrict__ O) {
  int id = blockIdx.x * TPB + threadIdx.x;  // 16*256*128 octet tasks
  int j = id & 127, c = (id >> 7) & 255, b = id >> 15;
  const float* p = V + ((size_t)(b * 256 + c)) * 1024 + j * 8;
  float4 f0 = *(const float4*)p;
  float4 f1 = *(const float4*)(p + 4);
  u16x8 h8;
  h8[0] = f2bf(f0.x); h8[1] = f2bf(f0.y); h8[2] = f2bf(f0.z); h8[3] = f2bf(f0.w);
  h8[4] = f2bf(f1.x); h8[5] = f2bf(f1.y); h8[6] = f2bf(f1.z); h8[7] = f2bf(f1.w);
  size_t rowbase = ((size_t)(b * 256 + c)) * 2048;  // bytes
  int byteoff = (j * 16) ^ ((c & 7) << 4);
  *(u16x8*)((char*)O + rowbase + byteoff) = h8;
}

// ---------------- fused non-local attention via bf16 MFMA, adds into out in-place ----------------
// grid (16 n-tiles, 16 b), block 256 = 4 waves x 16 query rows. m-loop in 64-key tiles.
// QK^T 3-pass hi/lo split (fp32-level dist); softmax in regs; P->LDS bf16; PV MFMA.
__global__ __launch_bounds__(TPB, 2) void attn_mfma(
    const unsigned short* __restrict__ qth, const unsigned short* __restrict__ qtl,
    const unsigned short* __restrict__ kth, const unsigned short* __restrict__ ktl,
    const unsigned short* __restrict__ vt,
    const float* __restrict__ q2g, const float* __restrict__ k2g,
    const float* __restrict__ sigp, float* __restrict__ out) {
  __shared__ unsigned short ksh[64 * 128], ksl[64 * 128];  // K tile [m][c] hi/lo
  __shared__ unsigned short vsm[256 * 64];                 // V tile [c'][m]
  __shared__ unsigned short pls[4][16 * 64];               // per-wave P [n][m]
  const int tid = threadIdx.x;
  const int b = blockIdx.y;
  const int n0 = blockIdx.x * 64;
  const int w = tid >> 6, lane = tid & 63;
  const int l15 = lane & 15, cg = lane >> 4;
  const float sg = *sigp;
  const float inv2s = 0.5f / (sg * sg);

  // Q A-frags: per-lane global reads (row = n0 + w*16 + l15, swizzled rows)
  const int nq = n0 + w * 16 + l15;
  bf16x8 qh[4], ql[4];
  {
    const char* qrh = (const char*)qth + ((size_t)(b * 1024 + nq)) * 256;
    const char* qrl = (const char*)qtl + ((size_t)(b * 1024 + nq)) * 256;
    int sw = (nq & 7) << 4;
#pragma unroll
    for (int kc = 0; kc < 4; ++kc) {
      int o = (kc * 64 + cg * 16) ^ sw;
      qh[kc] = *(const bf16x8*)(qrh + o);
      ql[kc] = *(const bf16x8*)(qrl + o);
    }
  }
  // q2 for D-rows n = n0 + w*16 + cg*4 + r
  float q2r[4];
#pragma unroll
  for (int r = 0; r < 4; ++r) q2r[r] = q2g[b * 1024 + n0 + w * 16 + cg * 4 + r];
  float dsum[4] = {0.f, 0.f, 0.f, 0.f};
  f32x4 acc[16];
#pragma unroll
  for (int cf = 0; cf < 16; ++cf)
#pragma unroll
    for (int r = 0; r < 4; ++r) acc[cf][r] = 0.f;

  const unsigned short* kh_g = kth + ((size_t)b * 1024) * 128;
  const unsigned short* kl_g = ktl + ((size_t)b * 1024) * 128;
  const unsigned short* v_g = vt + ((size_t)b * 256) * 1024;

  uint4 stg[16];
  auto load_tile = [&](int m0) {
#pragma unroll
    for (int i = 0; i < 4; ++i) {
      int off = (w + 4 * i) * 512 + lane * 8;
      stg[i] = *(const uint4*)(kh_g + (size_t)m0 * 128 + off);
      stg[4 + i] = *(const uint4*)(kl_g + (size_t)m0 * 128 + off);
    }
#pragma unroll
    for (int i = 0; i < 8; ++i) {
      int ch = w + 4 * i;
      int cp = ch * 8 + (lane >> 3);
      stg[8 + i] = *(const uint4*)(v_g + (size_t)cp * 1024 + m0 + (lane & 7) * 8);
    }
  };
  auto write_tile = [&]() {
#pragma unroll
    for (int i = 0; i < 4; ++i) {
      int off = (w + 4 * i) * 512 + lane * 8;
      *(uint4*)(ksh + off) = stg[i];
      *(uint4*)(ksl + off) = stg[4 + i];
    }
#pragma unroll
    for (int i = 0; i < 8; ++i) {
      int off = (w + 4 * i) * 512 + lane * 8;
      *(uint4*)(vsm + off) = stg[8 + i];
    }
  };

  load_tile(0);
  write_tile();
  __syncthreads();

  char* pmy = (char*)pls[w];
  const int psw = (l15 & 7) << 4;

  for (int t = 0; t < 16; ++t) {
    const int m0 = t * 64;
    // k2 at m = m0 + mf*16 + l15
    float k2r[4];
#pragma unroll
    for (int mf = 0; mf < 4; ++mf) k2r[mf] = k2g[b * 1024 + m0 + mf * 16 + l15];
    if (t < 15) load_tile(m0 + 64);  // prefetch next tile into regs (hidden under compute)

    // QK^T: D[n=cg*4+r][m=l15+16mf], 3-pass split
    f32x4 s[4];
#pragma unroll
    for (int mf = 0; mf < 4; ++mf)
#pragma unroll
      for (int r = 0; r < 4; ++r) s[mf][r] = 0.f;
#pragma unroll
    for (int mf = 0; mf < 4; ++mf) {
      const char* krh = (const char*)ksh + (mf * 16 + l15) * 256;
      const char* krl = (const char*)ksl + (mf * 16 + l15) * 256;
      int sw = ((mf * 16 + l15) & 7) << 4;
#pragma unroll
      for (int kc = 0; kc < 4; ++kc) {
        int o = (kc * 64 + cg * 16) ^ sw;
        bf16x8 kh8 = *(const bf16x8*)(krh + o);
        bf16x8 kl8 = *(const bf16x8*)(krl + o);
        s[mf] = __builtin_amdgcn_mfma_f32_16x16x32_bf16(qh[kc], kh8, s[mf], 0, 0, 0);
        s[mf] = __builtin_amdgcn_mfma_f32_16x16x32_bf16(qh[kc], kl8, s[mf], 0, 0, 0);
        s[mf] = __builtin_amdgcn_mfma_f32_16x16x32_bf16(ql[kc], kh8, s[mf], 0, 0, 0);
      }
    }
    // softmax numerators p = exp(exp(-dist^2/2s^2)); write P[n][m] bf16 (wave-private)
#pragma unroll
    for (int mf = 0; mf < 4; ++mf) {
      int mloc = mf * 16 + l15;
#pragma unroll
      for (int r = 0; r < 4; ++r) {
        float d = q2r[r] + k2r[mf] - 2.f * s[mf][r];
        float sim = __expf(-d * inv2s);
        float p = __expf(sim);
        dsum[r] += p;
        int nl = cg * 4 + r;
        *(unsigned short*)(pmy + nl * 128 + ((mloc * 2) ^ ((nl & 7) << 4))) = f2bf(p);
      }
    }
    // PV: A = P (lane l15 = n), B = V tile
    bf16x8 pa[2];
#pragma unroll
    for (int kc2 = 0; kc2 < 2; ++kc2)
      pa[kc2] = *(const bf16x8*)(pmy + l15 * 128 + ((kc2 * 64 + cg * 16) ^ psw));
#pragma unroll
    for (int cf = 0; cf < 16; ++cf) {
      int cp = cf * 16 + l15;
      const char* vrow = (const char*)vsm + cp * 128;
      int sw = (cp & 7) << 4;
#pragma unroll
      for (int kc2 = 0; kc2 < 2; ++kc2) {
        bf16x8 vb8 = *(const bf16x8*)(vrow + ((kc2 * 64 + cg * 16) ^ sw));
        acc[cf] = __builtin_amdgcn_mfma_f32_16x16x32_bf16(pa[kc2], vb8, acc[cf], 0, 0, 0);
      }
    }
    __syncthreads();            // all waves done reading tile t
    if (t < 15) write_tile();   // stage tile t+1
    __syncthreads();            // tile t+1 visible
  }

  // finalize denominators (sum over the 16 lanes of each cg group)
#pragma unroll
  for (int r = 0; r < 4; ++r) {
    dsum[r] += __shfl_xor(dsum[r], 1);
    dsum[r] += __shfl_xor(dsum[r], 2);
    dsum[r] += __shfl_xor(dsum[r], 4);
    dsum[r] += __shfl_xor(dsum[r], 8);
  }
  // out[b][n][c'] flat add (raw [B,N,C] -> [B,C,H,W] reinterpret)
#pragma unroll
  for (int r = 0; r < 4; ++r) {
    float rv = 1.f / dsum[r];
    size_t base = (size_t)b * 262144 + (size_t)(n0 + w * 16 + cg * 4 + r) * 256;
#pragma unroll
    for (int cf = 0; cf < 16; ++cf) {
      size_t idx = base + cf * 16 + l15;
      out[idx] += acc[cf][r] * rv;
    }
  }
}

// ---------------- launcher ----------------
extern "C" void kernel_launch(void* const* d_in, const int* in_sizes, int n_in,
                              void* d_out, int out_size, void* d_ws, size_t ws_size,
                              hipStream_t stream) {
  (void)in_sizes; (void)n_in; (void)out_size; (void)ws_size;
  const float* x      = (const float*)d_in[0];
  const float* w1     = (const float*)d_in[1];
  const float* b1     = (const float*)d_in[2];
  const float* w3     = (const float*)d_in[3];
  const float* b3     = (const float*)d_in[4];
  const float* w5     = (const float*)d_in[5];
  const float* b5     = (const float*)d_in[6];
  const float* wq     = (const float*)d_in[7];
  const float* bq     = (const float*)d_in[8];
  const float* wk     = (const float*)d_in[9];
  const float* bk     = (const float*)d_in[10];
  const float* wv     = (const float*)d_in[11];
  const float* bv     = (const float*)d_in[12];
  const float* sigma  = (const float*)d_in[13];
  const float* ca_w1  = (const float*)d_in[14];
  const float* ca_w2  = (const float*)d_in[15];
  const float* sa_w   = (const float*)d_in[16];
  const float* tail_w = (const float*)d_in[17];
  const float* tail_b = (const float*)d_in[18];
  float* out_f = (float*)d_out;

  float* ws = (float*)d_ws;
  float* outb  = ws;  ws += 4194304;
  float* cbuf  = ws;  ws += 4194304;
  float* qb    = ws;  ws += 2097152;   // fp32 q; later reused as vt (bf16 V)
  float* kb    = ws;  ws += 2097152;
  float* vb    = ws;  ws += 4194304;
  float* b_eff = ws;  ws += 256;
  float* avg   = ws;  ws += 4096;
  float* mxp   = ws;  ws += 4096;
  float* cab   = ws;  ws += 4096;
  float* sain  = ws;  ws += 32768;
  float* sab   = ws;  ws += 16384;
  float* q2b   = ws;  ws += 16384;
  float* k2b   = ws;  ws += 16384;
  unsigned short* us = (unsigned short*)ws;
  unsigned short* wfh = us;  us += 1638400;
  unsigned short* wfl = us;  us += 1638400;
  unsigned short* xhb = us;  us += 4194304;   // reused: qth+qtl after conv
  unsigned short* xlb = us;  us += 4194304;   // reused: kth+ktl after conv
  unsigned short* qth = xhb;
  unsigned short* qtl = xhb + 2097152;
  unsigned short* kth = xlb;
  unsigned short* ktl = xlb + 2097152;
  unsigned short* vtb = (unsigned short*)qb;  // 8MB region, exact fit

  // 1. prep + fused 5x5 conv (bf16 MFMA, 3-pass split precision)
  hipLaunchKernelGGL(prep_w, dim3(6400), dim3(TPB), 0, stream,
                     w1, b1, w3, b3, w5, b5, wfh, wfl, b_eff);
  hipLaunchKernelGGL(prep_x, dim3(2048), dim3(TPB), 0, stream, x, xhb, xlb);
  hipLaunchKernelGGL(conv5_mfma, dim3(8, 4, 16), dim3(TPB), 0, stream,
                     xhb, xlb, wfh, wfl, b_eff, outb);
  // 2. CBAM
  hipLaunchKernelGGL(pool_avgmax, dim3(4096), dim3(TPB), 0, stream, outb, avg, mxp);
  hipLaunchKernelGGL(ca_mlp, dim3(16), dim3(TPB), 0, stream, avg, mxp, ca_w1, ca_w2, cab);
  hipLaunchKernelGGL(mul_ca, dim3(4096), dim3(TPB), 0, stream, outb, cab, cbuf);
  hipLaunchKernelGGL(spatial_pool, dim3(64), dim3(TPB), 0, stream, cbuf, sain);
  hipLaunchKernelGGL(sa_conv, dim3(64), dim3(TPB), 0, stream, sain, sa_w, sab);
  hipLaunchKernelGGL(mul_sa, dim3(4096), dim3(TPB), 0, stream, cbuf, sab);
  // 3. non-local attention: q/k/v GEMMs, transposes+converts, fused MFMA attention
  hipLaunchKernelGGL(gemm1x1, dim3(16, 2, 16), dim3(TPB), 0, stream,
                     wq, bq, outb, outb, qb, 128, 256);
  hipLaunchKernelGGL(gemm1x1, dim3(16, 2, 16), dim3(TPB), 0, stream,
                     wk, bk, outb, outb, kb, 128, 256);
  hipLaunchKernelGGL(gemm1x1, dim3(16, 4, 16), dim3(TPB), 0, stream,
                     wv, bv, outb, outb, vb, 256, 256);
  hipLaunchKernelGGL(xpose_qk, dim3(16, 16), dim3(TPB), 0, stream, qb, qth, qtl);
  hipLaunchKernelGGL(xpose_qk, dim3(16, 16), dim3(TPB), 0, stream, kb, kth, ktl);
  hipLaunchKernelGGL(sqnorm, dim3(64), dim3(TPB), 0, stream, qb, q2b, 128);
  hipLaunchKernelGGL(sqnorm, dim3(64), dim3(TPB), 0, stream, kb, k2b, 128);
  hipLaunchKernelGGL(conv_v, dim3(2048), dim3(TPB), 0, stream, vb, vtb);  // overwrites qb (dead)
  hipLaunchKernelGGL(attn_mfma, dim3(16, 16), dim3(TPB), 0, stream,
                     qth, qtl, kth, ktl, vtb, q2b, k2b, sigma, outb);
  // 4. tail conv over concat [cbam_out, non_local]
  hipLaunchKernelGGL(gemm1x1, dim3(16, 4, 16), dim3(TPB), 0, stream,
                     tail_w, tail_b, cbuf, outb, out_f, 256, 512);
}